// Round 6
// baseline (294.702 us; speedup 1.0000x reference)
//
#include <hip/hip_runtime.h>
#include <hip/hip_bf16.h>

#define D 1024
#define SLEN 2048
#define BS 16
#define MROWS (BS*SLEN)   // 32768

typedef __attribute__((ext_vector_type(8))) short short8;
typedef __attribute__((ext_vector_type(4))) float f32x4;

__device__ __forceinline__ short f2bf(float f) {
  __hip_bfloat16 h = __float2bfloat16(f);
  return __builtin_bit_cast(short, h);
}

// non-temporal float4 load: streaming data (zero reuse) -> don't allocate in
// L2/L3 so the 2 MB WkT stays L2-resident for the B stream.
__device__ __forceinline__ float4 ntload4(const float* p) {
  f32x4 v = __builtin_nontemporal_load((const f32x4*)p);
  float4 r; r.x = v.x; r.y = v.y; r.z = v.z; r.w = v.w; return r;
}

// ---------------- Kernel 1: Wk (k,n) fp32 -> blocked bf16 WkT ----------------
// WkT[(u*1024 + n)*8 + j] = bf16(Wk[(u*8+j)*1024 + n]), u=0..127.
// 16B slot (u,n) = B[n][k=u*8..u*8+7] = one MFMA B k-unit.
__global__ __launch_bounds__(256) void wk_prep(const float* __restrict__ Wk,
                                               short* __restrict__ WkT) {
  const int g = blockIdx.x;        // 0..127
  const int t = threadIdx.x;
#pragma unroll
  for (int it = 0; it < 4; ++it) {
    const int n = it*256 + t;
    short8 p;
#pragma unroll
    for (int j = 0; j < 8; ++j)
      p[j] = f2bf(Wk[(size_t)(g*8 + j)*D + n]);
    *(short8*)(WkT + ((size_t)g*D + n)*8) = p;
  }
}

// ---------------- Kernel 2: energy GEMM, barrier-free K-loop ----------------
// Block = 64 M-rows x full K in LDS (staged once, bf16, padded row stride 129
// slots). 8 waves x 128 cols cover N=1024 -> complete e rows, no atomics.
// B streamed L2->registers, prefetched 1 k-step ahead, no barriers in K-loop.
// A staged with NON-TEMPORAL loads (streaming) to protect WkT's L2 residency.
// Register budget note: acc = 128 AGPR, fa/fb+addr ~= 128 VGPR -> exactly
// 2 waves/SIMD (matches LDS cap of 1 block/CU). Do NOT deepen the pipeline.
__global__ __launch_bounds__(512, 2) void energy_gemm(
    const float* __restrict__ states, const short* __restrict__ WkT,
    const float* __restrict__ bk, const float* __restrict__ We,
    float* __restrict__ eraw)
{
  __shared__ short Al[64 * 129 * 8];   // 132 KB: slot(row,u) = row*129 + u

  const int tid  = threadIdx.x;
  const int w    = tid >> 6;        // wave 0..7 -> col group w*128
  const int lane = tid & 63;
  const int quad = lane >> 4;       // k-unit within 32-chunk
  const int l16  = lane & 15;
  const int m0   = blockIdx.x * 64;

  // ---- one-time A staging: 64 rows x 1024 k, fp32 -> bf16 (non-temporal) ----
  {
    const int row = tid >> 3;
    const int u0  = tid & 7;
    const float* Ag = states + (size_t)(m0 + row)*D;
#pragma unroll
    for (int i = 0; i < 16; ++i) {
      const int u = u0 + i*8;
      float4 x0 = ntload4(Ag + u*8);
      float4 x1 = ntload4(Ag + u*8 + 4);
      short8 p;
      p[0]=f2bf(x0.x); p[1]=f2bf(x0.y); p[2]=f2bf(x0.z); p[3]=f2bf(x0.w);
      p[4]=f2bf(x1.x); p[5]=f2bf(x1.y); p[6]=f2bf(x1.z); p[7]=f2bf(x1.w);
      *(short8*)(Al + ((size_t)row*129 + u)*8) = p;
    }
  }
  __syncthreads();

  f32x4 acc[2][4][4];
#pragma unroll
  for (int nc = 0; nc < 2; ++nc)
#pragma unroll
    for (int mi = 0; mi < 4; ++mi)
#pragma unroll
      for (int ni = 0; ni < 4; ++ni)
        acc[nc][mi][ni] = (f32x4){0.f, 0.f, 0.f, 0.f};

  const short* bbase = WkT + ((size_t)quad*D + w*128 + l16)*8;   // + ks*32768 + nc*512 + ni*128
  const short* abase = Al + ((size_t)l16*129 + quad)*8;          // + mi*16512 + ks*32

#define LOADB(ks, buf)                                                   \
  {                                                                      \
    const short* bp = bbase + (size_t)(ks)*32768;                        \
    _Pragma("unroll")                                                    \
    for (int nc = 0; nc < 2; ++nc)                                       \
      _Pragma("unroll")                                                  \
      for (int ni = 0; ni < 4; ++ni)                                     \
        buf[nc*4 + ni] = *(const short8*)(bp + nc*512 + ni*128);         \
  }

#define LOADA(ks, buf)                                                   \
  {                                                                      \
    _Pragma("unroll")                                                    \
    for (int mi = 0; mi < 4; ++mi)                                       \
      buf[mi] = *(const short8*)(abase + mi*16512 + (ks)*32);            \
  }

#define MFMAS(fa, fb)                                                    \
  {                                                                      \
    _Pragma("unroll")                                                    \
    for (int nc = 0; nc < 2; ++nc)                                       \
      _Pragma("unroll")                                                  \
      for (int mi = 0; mi < 4; ++mi)                                     \
        _Pragma("unroll")                                                \
        for (int ni = 0; ni < 4; ++ni)                                   \
          acc[nc][mi][ni] = __builtin_amdgcn_mfma_f32_16x16x32_bf16(     \
              fa[mi], fb[nc*4 + ni], acc[nc][mi][ni], 0, 0, 0);          \
  }

  short8 fa0[4], fa1[4], fb0[8], fb1[8];
  LOADA(0, fa0); LOADB(0, fb0);
#pragma unroll
  for (int kk = 0; kk < 16; ++kk) {
    LOADA(2*kk + 1, fa1); LOADB(2*kk + 1, fb1);
    MFMAS(fa0, fb0);
    if (kk < 15) { LOADA(2*kk + 2, fa0); LOADB(2*kk + 2, fb0); }
    MFMAS(fa1, fb1);
  }

  // ---- epilogue: esum[row] += tanh(relu(c + bk[n])) * We_k[n] ----
  float esum[16];
#pragma unroll
  for (int q = 0; q < 16; ++q) esum[q] = 0.f;
#pragma unroll
  for (int nc = 0; nc < 2; ++nc)
#pragma unroll
    for (int ni = 0; ni < 4; ++ni) {
      const int n = w*128 + nc*64 + ni*16 + l16;
      const float bkv = bk[n];
      const float wev = We[D + n];
#pragma unroll
      for (int mi = 0; mi < 4; ++mi)
#pragma unroll
        for (int r = 0; r < 4; ++r) {
          float x = acc[nc][mi][ni][r] + bkv;
          x = fmaxf(x, 0.f);
          float ex = __expf(2.f * x);
          float th = 1.f - 2.f/(ex + 1.f);
          esum[mi*4 + r] += th * wev;
        }
    }
#pragma unroll
  for (int dd = 1; dd < 16; dd <<= 1)
#pragma unroll
    for (int q = 0; q < 16; ++q)
      esum[q] += __shfl_xor(esum[q], dd, 64);

  __syncthreads();                    // all waves done reading Al
  float* red = (float*)Al;            // [64 rows][8 waves]
  if (l16 == 0) {
#pragma unroll
    for (int mi = 0; mi < 4; ++mi)
#pragma unroll
      for (int r = 0; r < 4; ++r)
        red[(mi*16 + quad*4 + r)*8 + w] = esum[mi*4 + r];
  }
  __syncthreads();
  if (tid < 64) {
    float s = 0.f;
#pragma unroll
    for (int wi = 0; wi < 8; ++wi) s += red[tid*8 + wi];
    eraw[m0 + tid] = s;
  }
#undef LOADB
#undef LOADA
#undef MFMAS
}

// ---------------- Kernel 3: row softmax eraw -> wts (d_out) ----------------
__global__ __launch_bounds__(256) void softmax_rows(
    const float* __restrict__ eraw, float* __restrict__ wts) {
  const int b = blockIdx.x, t = threadIdx.x;
  __shared__ float red[256];
  float v[8];
  float m = -1e30f;
#pragma unroll
  for (int j = 0; j < 8; ++j) {
    v[j] = eraw[(size_t)b*SLEN + j*256 + t];
    m = fmaxf(m, v[j]);
  }
  red[t] = m; __syncthreads();
  for (int s = 128; s > 0; s >>= 1) {
    if (t < s) red[t] = fmaxf(red[t], red[t+s]);
    __syncthreads();
  }
  m = red[0];
  __syncthreads();
  float sum = 0.f;
#pragma unroll
  for (int j = 0; j < 8; ++j) { v[j] = __expf(v[j] - m); sum += v[j]; }
  red[t] = sum; __syncthreads();
  for (int s = 128; s > 0; s >>= 1) {
    if (t < s) red[t] += red[t+s];
    __syncthreads();
  }
  const float inv = 1.f / red[0];
#pragma unroll
  for (int j = 0; j < 8; ++j)
    wts[(size_t)b*SLEN + j*256 + t] = v[j] * inv;
}

// ---------------- Kernel 4: attn partials, 1024 blocks (BW-saturating) ------
// part[(b*64+sc)*1024 + d] = sum_{32 s in chunk} w[b,s]*states[b,s,d]
__global__ __launch_bounds__(256) void attn_partial(
    const float* __restrict__ states, const float* __restrict__ wts,
    float* __restrict__ part)
{
  const int sc = blockIdx.x;   // 0..63 (32 s each)
  const int b  = blockIdx.y;   // 0..15
  const int t  = threadIdx.x;
  __shared__ float wsh[32];
  if (t < 32) wsh[t] = wts[(size_t)b*SLEN + sc*32 + t];
  __syncthreads();
  const float* sp = states + ((size_t)b*SLEN + sc*32)*D + t*4;
  float ax = 0.f, ay = 0.f, az = 0.f, aw = 0.f;
#pragma unroll
  for (int s = 0; s < 32; ++s) {
    float4 x = ntload4(sp + (size_t)s*D);
    const float wv = wsh[s];
    ax = fmaf(wv, x.x, ax);
    ay = fmaf(wv, x.y, ay);
    az = fmaf(wv, x.z, az);
    aw = fmaf(wv, x.w, aw);
  }
  float4 o; o.x = ax; o.y = ay; o.z = az; o.w = aw;
  *(float4*)(part + ((size_t)(b*64 + sc))*D + t*4) = o;
}

// ---------------- Kernel 5: reduce 64 partials per batch ----------------
__global__ __launch_bounds__(256) void attn_final(
    const float* __restrict__ part, float* __restrict__ attn)
{
  const int b = blockIdx.x, t = threadIdx.x;
  float4 s = {0.f, 0.f, 0.f, 0.f};
#pragma unroll
  for (int sc = 0; sc < 64; ++sc) {
    float4 v = *(const float4*)(part + ((size_t)(b*64 + sc))*D + t*4);
    s.x += v.x; s.y += v.y; s.z += v.z; s.w += v.w;
  }
  *(float4*)(attn + (size_t)b*D + t*4) = s;
}

extern "C" void kernel_launch(void* const* d_in, const int* in_sizes, int n_in,
                              void* d_out, int out_size, void* d_ws, size_t ws_size,
                              hipStream_t stream) {
  // inputs: 0=query 1=states 2=Wq 3=bq 4=Wk 5=bk 6=We 7=be
  // q-path terms are constant per softmax row -> cancel; dead code.
  const float* states = (const float*)d_in[1];
  const float* Wk     = (const float*)d_in[4];
  const float* bk     = (const float*)d_in[5];
  const float* We     = (const float*)d_in[6];
  float* out = (float*)d_out;            // [0:32768) attn_weights, [32768:49152) attn

  short* WkT  = (short*)d_ws;                                         // 2 MB
  float* eraw = (float*)((char*)d_ws + (size_t)D*D*sizeof(short));    // 128 KB
  float* part = (float*)((char*)d_ws + (size_t)D*D*sizeof(short)
                                     + (size_t)MROWS*sizeof(float));  // 4 MB

  (void)in_sizes; (void)n_in; (void)out_size; (void)ws_size;

  wk_prep<<<128, 256, 0, stream>>>(Wk, WkT);
  energy_gemm<<<MROWS/64, 512, 0, stream>>>(states, WkT, bk, We, eraw);
  softmax_rows<<<BS, 256, 0, stream>>>(eraw, out);
  attn_partial<<<dim3(64, BS), 256, 0, stream>>>(states, out, part);
  attn_final<<<BS, 256, 0, stream>>>(part, out + MROWS);
}